// Round 23
// baseline (159.126 us; speedup 1.0000x reference)
//
#include <hip/hip_runtime.h>

// Armor: strict IEEE semantics. Arithmetic contract frozen (validated R13/R14):
// mul+add einsum -> pairwise pool -> seq-k FMA DCT -> scale mul -> recip-mul -> rintf.
#pragma float_control(precise, on)

// One block's 4-term sub-chain for k-group g (k ascending, single acc, fmaf).
// b fetched as a lane-uniform float4 from LDS (native same-address broadcast).
#define STEP4(i, g, WV) {                                               \
    const float4 bq = *(const float4*)(bp##i + (g) * 4);                \
    ac##i = fmaf(bq.x, WV.x, ac##i); ac##i = fmaf(bq.y, WV.y, ac##i);   \
    ac##i = fmaf(bq.z, WV.z, ac##i); ac##i = fmaf(bq.w, WV.w, ac##i); }

// Depth-2 pipelined weight loads from the transposed table: group g consumes
// WCUR while WNXT's dwordx4 (imm offset, lane-contiguous) is in flight.
#define GRP(g, WCUR)                                                    \
    STEP4(0, g, WCUR) STEP4(1, g, WCUR) STEP4(2, g, WCUR)               \
    STEP4(3, g, WCUR) STEP4(4, g, WCUR) STEP4(5, g, WCUR)

// Per-lane SETUP (R19 regime: keeps allocator at VGPR~64, pipelining deep).
#define SETUP(i) \
    const float* bp##i; float qr##i; size_t ob##i; float ac##i = 0.0f;   \
    { const int blk = wave * 6 + i;                                      \
      if (blk < 16) {                                                    \
          bp##i = &ylds[blk * 64]; qr##i = rqy;                          \
          const int gbr = ty * 4 + (blk >> 2);                           \
          const int gbc = tx * 4 + (blk & 3);                            \
          ob##i = ((size_t)img * 16384 + (size_t)(gbr * 128 + gbc)) * 64;\
      } else {                                                           \
          const int cb = blk - 16;                                       \
          bp##i = &clds[cb * 64]; qr##i = rqc;                           \
          const int cc = cb & 3;                                         \
          const int gbr = ty * 2 + (cc >> 1);                            \
          const int gbc = tx * 2 + (cc & 1);                             \
          ob##i = (size_t)16777216u + (size_t)(cb >> 2) * 4194304u       \
                + ((size_t)img * 4096 + (size_t)(gbr * 64 + gbc)) * 64;  \
      } }

#define FIN(i) { const float dd = scale_l * ac##i;                       \
                 out[ob##i + lane] = rintf(dd * qr##i); }

// Prologue: transpose the 64x64 DCT table once (wt[l*64+k] = dct[k*64+l]).
extern "C" __global__ void __launch_bounds__(256)
wtranspose(const float* __restrict__ dct, float* __restrict__ wt)
{
    const int i = blockIdx.x * 256 + threadIdx.x;   // 4096 elements
    wt[(i & 63) * 64 + (i >> 6)] = dct[i];
}

extern "C" __global__ void __launch_bounds__(256, 8)
jpeg_compress(const float* __restrict__ image,
              const float* __restrict__ matrix,
              const float* __restrict__ shiftv,
              const float* __restrict__ y_table,
              const float* __restrict__ c_table,
              const float* __restrict__ wt,         // transposed weights (d_ws)
              const float* __restrict__ dct_scale,
              const int*   __restrict__ factor,
              float* __restrict__ out)
{
    const int t    = threadIdx.x;
    const int lane = t & 63;
    const int wave = t >> 6;
    const int wg   = blockIdx.x;
    const int img  = wg >> 10;
    const int tile = wg & 1023;
    const int ty   = tile >> 5;
    const int tx   = tile & 31;

    __shared__ __align__(16) float ylds[16 * 64];   // 16 Y blocks, block-major
    __shared__ __align__(16) float clds[8 * 64];    // 4 Cb + 4 Cr blocks

    const float m00 = matrix[0], m01 = matrix[1], m02 = matrix[2];
    const float m10 = matrix[3], m11 = matrix[4], m12 = matrix[5];
    const float m20 = matrix[6], m21 = matrix[7], m22 = matrix[8];
    const float sh0 = shiftv[0], sh1 = shiftv[1], sh2 = shiftv[2];

    // ---- phase 1: load 32x32 RGB tile, YCbCr, pool chroma, stage to LDS ----
    const int row = t >> 3;            // 0..31
    const int c0  = (t & 7) << 2;      // 0..28 step 4
    const float* p = image + (size_t)img * 3145728u
                   + (size_t)(ty * 32 + row) * 1024 + (size_t)(tx * 32 + c0);
    float4 R4 = *(const float4*)p;
    float4 G4 = *(const float4*)(p + 1048576);
    float4 B4 = *(const float4*)(p + 2097152);

    float yv[4], cbv[4], crv[4];
    {
        #pragma clang fp contract(off)
        float Rr[4] = {R4.x, R4.y, R4.z, R4.w};
        float Gg[4] = {G4.x, G4.y, G4.z, G4.w};
        float Bb[4] = {B4.x, B4.y, B4.z, B4.w};
        #pragma unroll
        for (int j = 0; j < 4; ++j) {
            float R = Rr[j] * 255.0f, G = Gg[j] * 255.0f, B = Bb[j] * 255.0f;
            // VALIDATED: einsum = sequential c, mul then add (no fma), + shift separate
            yv[j]  = (((R * m00 + G * m10) + B * m20) + sh0) - 128.0f;
            cbv[j] =  ((R * m01 + G * m11) + B * m21) + sh1;
            crv[j] =  ((R * m02 + G * m12) + B * m22) + sh2;
        }
    }

    {
        const int yblk = ((row >> 3) << 2) + (c0 >> 3);
        const int yk   = ((row & 7) << 3) + (c0 & 7);
        *(float4*)&ylds[yblk * 64 + yk] = make_float4(yv[0], yv[1], yv[2], yv[3]);
    }

    float bcb[4], bcr[4];
    #pragma unroll
    for (int j = 0; j < 4; ++j) {
        bcb[j] = __shfl_down(cbv[j], 8, 64);
        bcr[j] = __shfl_down(crv[j], 8, 64);
    }
    if ((row & 1) == 0) {
        #pragma clang fp contract(off)
        // VALIDATED: pairwise pool (x00+x01)+(x10+x11), exact /4, -128
        float p0cb = (((cbv[0] + cbv[1]) + (bcb[0] + bcb[1])) / 4.0f) - 128.0f;
        float p1cb = (((cbv[2] + cbv[3]) + (bcb[2] + bcb[3])) / 4.0f) - 128.0f;
        float p0cr = (((crv[0] + crv[1]) + (bcr[0] + bcr[1])) / 4.0f) - 128.0f;
        float p1cr = (((crv[2] + crv[3]) + (bcr[2] + bcr[3])) / 4.0f) - 128.0f;
        const int pr = row >> 1;           // 0..15
        const int pc = (t & 7) << 1;       // 0..14 step 2
        const int cblk = ((pr >> 3) << 1) + (pc >> 3);
        const int kk = ((pr & 7) << 3) + (pc & 7);
        clds[cblk * 64 + kk]           = p0cb;
        clds[cblk * 64 + kk + 1]       = p1cb;
        clds[(4 + cblk) * 64 + kk]     = p0cr;
        clds[(4 + cblk) * 64 + kk + 1] = p1cr;
    }
    __syncthreads();

    const float* wlane = wt + lane * 64;  // lane-contiguous weights, imm offsets

    const float scale_l = dct_scale[lane];
    const float fac = (float)factor[0];
    // VALIDATED: reciprocal-multiply quantize, f32
    const float rqy = 1.0f / (y_table[lane] * fac);
    const float rqc = 1.0f / (c_table[lane] * fac);

    // ---- phase 2: 6 blocks, ILP-6, depth-2 pipelined weight loads ----
    SETUP(0) SETUP(1) SETUP(2) SETUP(3) SETUP(4) SETUP(5)

    float4 wva = *(const float4*)(wlane + 0);
    float4 wvb = *(const float4*)(wlane + 4);
    GRP(0,  wva) wva = *(const float4*)(wlane + 8);
    GRP(1,  wvb) wvb = *(const float4*)(wlane + 12);
    GRP(2,  wva) wva = *(const float4*)(wlane + 16);
    GRP(3,  wvb) wvb = *(const float4*)(wlane + 20);
    GRP(4,  wva) wva = *(const float4*)(wlane + 24);
    GRP(5,  wvb) wvb = *(const float4*)(wlane + 28);
    GRP(6,  wva) wva = *(const float4*)(wlane + 32);
    GRP(7,  wvb) wvb = *(const float4*)(wlane + 36);
    GRP(8,  wva) wva = *(const float4*)(wlane + 40);
    GRP(9,  wvb) wvb = *(const float4*)(wlane + 44);
    GRP(10, wva) wva = *(const float4*)(wlane + 48);
    GRP(11, wvb) wvb = *(const float4*)(wlane + 52);
    GRP(12, wva) wva = *(const float4*)(wlane + 56);
    GRP(13, wvb) wvb = *(const float4*)(wlane + 60);
    GRP(14, wva)
    GRP(15, wvb)

    FIN(0) FIN(1) FIN(2) FIN(3) FIN(4) FIN(5)
}

extern "C" void kernel_launch(void* const* d_in, const int* in_sizes, int n_in,
                              void* d_out, int out_size, void* d_ws, size_t ws_size,
                              hipStream_t stream)
{
    const float* image   = (const float*)d_in[0];
    const float* matrix  = (const float*)d_in[1];
    const float* shiftv  = (const float*)d_in[2];
    const float* y_table = (const float*)d_in[3];
    const float* c_table = (const float*)d_in[4];
    const float* dct_t   = (const float*)d_in[5];
    const float* dct_s   = (const float*)d_in[6];
    const int*   factor  = (const int*)d_in[7];
    float* wt = (float*)d_ws;                        // 16 KB transposed weights

    wtranspose<<<dim3(16), dim3(256), 0, stream>>>(dct_t, wt);
    jpeg_compress<<<dim3(16384), dim3(256), 0, stream>>>(
        image, matrix, shiftv, y_table, c_table, wt, dct_s, factor,
        (float*)d_out);
}

// Round 24
// 94.900 us; speedup vs baseline: 1.6768x; 1.6768x over previous
//
#include <hip/hip_runtime.h>

// Armor: strict IEEE semantics. Arithmetic contract frozen (validated R13/R14):
// mul+add einsum -> pairwise pool -> seq-k FMA DCT -> scale mul -> recip-mul -> rintf.
#pragma float_control(precise, on)

// One block's 4-term sub-chain for k-group g (k ascending, single acc, fmaf).
// b fetched as a lane-uniform float4 from LDS (native same-address broadcast).
#define STEP4(i, g, W0, W1, W2, W3) {                                   \
    const float4 bq = *(const float4*)(bp##i + (g) * 4);                \
    ac##i = fmaf(bq.x, W0, ac##i); ac##i = fmaf(bq.y, W1, ac##i);       \
    ac##i = fmaf(bq.z, W2, ac##i); ac##i = fmaf(bq.w, W3, ac##i); }

// Weights loaded AT USE from the L1-resident 16KB table. NOTE: the "messy"
// per-lane strided addressing here is LOAD-BEARING — it keeps the register
// allocator at VGPR 64 (vs 28-32 for "clean" schemes), which buys the
// scheduler pipelining depth. R20-R23 all regressed by simplifying this.
#define GROUP(g) {                                                      \
    const float W0 = dct_tensor[((g) * 4 + 0) * 64 + lane];             \
    const float W1 = dct_tensor[((g) * 4 + 1) * 64 + lane];             \
    const float W2 = dct_tensor[((g) * 4 + 2) * 64 + lane];             \
    const float W3 = dct_tensor[((g) * 4 + 3) * 64 + lane];             \
    STEP4(0, g, W0, W1, W2, W3) STEP4(1, g, W0, W1, W2, W3)             \
    STEP4(2, g, W0, W1, W2, W3) STEP4(3, g, W0, W1, W2, W3)             \
    STEP4(4, g, W0, W1, W2, W3) STEP4(5, g, W0, W1, W2, W3) }

// Per-lane SETUP (same rationale: keeps VGPR budget honest at 64).
#define SETUP(i) \
    const float* bp##i; float qr##i; size_t ob##i; float ac##i = 0.0f;   \
    { const int blk = wave * 6 + i;                                      \
      if (blk < 16) {                                                    \
          bp##i = &ylds[blk * 64]; qr##i = rqy;                          \
          const int gbr = ty * 4 + (blk >> 2);                           \
          const int gbc = tx * 4 + (blk & 3);                            \
          ob##i = ((size_t)img * 16384 + (size_t)(gbr * 128 + gbc)) * 64;\
      } else {                                                           \
          const int cb = blk - 16;                                       \
          bp##i = &clds[cb * 64]; qr##i = rqc;                           \
          const int cc = cb & 3;                                         \
          const int gbr = ty * 2 + (cc >> 1);                            \
          const int gbc = tx * 2 + (cc & 1);                             \
          ob##i = (size_t)16777216u + (size_t)(cb >> 2) * 4194304u       \
                + ((size_t)img * 4096 + (size_t)(gbr * 64 + gbc)) * 64;  \
      } }

#define FIN(i) { const float dd = scale_l * ac##i;                       \
                 out[ob##i + lane] = rintf(dd * qr##i); }

extern "C" __global__ void __launch_bounds__(256, 8)
jpeg_compress(const float* __restrict__ image,
              const float* __restrict__ matrix,
              const float* __restrict__ shiftv,
              const float* __restrict__ y_table,
              const float* __restrict__ c_table,
              const float* __restrict__ dct_tensor,
              const float* __restrict__ dct_scale,
              const int*   __restrict__ factor,
              float* __restrict__ out)
{
    const int t    = threadIdx.x;
    const int lane = t & 63;
    const int wave = t >> 6;
    const int wg   = blockIdx.x;
    const int img  = wg >> 10;
    const int tile = wg & 1023;
    const int ty   = tile >> 5;
    const int tx   = tile & 31;

    __shared__ __align__(16) float ylds[16 * 64];   // 16 Y blocks, block-major
    __shared__ __align__(16) float clds[8 * 64];    // 4 Cb + 4 Cr blocks

    const float m00 = matrix[0], m01 = matrix[1], m02 = matrix[2];
    const float m10 = matrix[3], m11 = matrix[4], m12 = matrix[5];
    const float m20 = matrix[6], m21 = matrix[7], m22 = matrix[8];
    const float sh0 = shiftv[0], sh1 = shiftv[1], sh2 = shiftv[2];

    // ---- phase 1: load 32x32 RGB tile, YCbCr, pool chroma, stage to LDS ----
    const int row = t >> 3;            // 0..31
    const int c0  = (t & 7) << 2;      // 0..28 step 4
    const float* p = image + (size_t)img * 3145728u
                   + (size_t)(ty * 32 + row) * 1024 + (size_t)(tx * 32 + c0);
    float4 R4 = *(const float4*)p;
    float4 G4 = *(const float4*)(p + 1048576);
    float4 B4 = *(const float4*)(p + 2097152);

    float yv[4], cbv[4], crv[4];
    {
        #pragma clang fp contract(off)
        float Rr[4] = {R4.x, R4.y, R4.z, R4.w};
        float Gg[4] = {G4.x, G4.y, G4.z, G4.w};
        float Bb[4] = {B4.x, B4.y, B4.z, B4.w};
        #pragma unroll
        for (int j = 0; j < 4; ++j) {
            float R = Rr[j] * 255.0f, G = Gg[j] * 255.0f, B = Bb[j] * 255.0f;
            // VALIDATED: einsum = sequential c, mul then add (no fma), + shift separate
            yv[j]  = (((R * m00 + G * m10) + B * m20) + sh0) - 128.0f;
            cbv[j] =  ((R * m01 + G * m11) + B * m21) + sh1;
            crv[j] =  ((R * m02 + G * m12) + B * m22) + sh2;
        }
    }

    {
        const int yblk = ((row >> 3) << 2) + (c0 >> 3);
        const int yk   = ((row & 7) << 3) + (c0 & 7);
        *(float4*)&ylds[yblk * 64 + yk] = make_float4(yv[0], yv[1], yv[2], yv[3]);
    }

    float bcb[4], bcr[4];
    #pragma unroll
    for (int j = 0; j < 4; ++j) {
        bcb[j] = __shfl_down(cbv[j], 8, 64);
        bcr[j] = __shfl_down(crv[j], 8, 64);
    }
    if ((row & 1) == 0) {
        #pragma clang fp contract(off)
        // VALIDATED: pairwise pool (x00+x01)+(x10+x11), exact /4, -128
        float p0cb = (((cbv[0] + cbv[1]) + (bcb[0] + bcb[1])) / 4.0f) - 128.0f;
        float p1cb = (((cbv[2] + cbv[3]) + (bcb[2] + bcb[3])) / 4.0f) - 128.0f;
        float p0cr = (((crv[0] + crv[1]) + (bcr[0] + bcr[1])) / 4.0f) - 128.0f;
        float p1cr = (((crv[2] + crv[3]) + (bcr[2] + bcr[3])) / 4.0f) - 128.0f;
        const int pr = row >> 1;           // 0..15
        const int pc = (t & 7) << 1;       // 0..14 step 2
        const int cblk = ((pr >> 3) << 1) + (pc >> 3);
        const int kk = ((pr & 7) << 3) + (pc & 7);
        clds[cblk * 64 + kk]           = p0cb;
        clds[cblk * 64 + kk + 1]       = p1cb;
        clds[(4 + cblk) * 64 + kk]     = p0cr;
        clds[(4 + cblk) * 64 + kk + 1] = p1cr;
    }
    __syncthreads();

    const float scale_l = dct_scale[lane];
    const float fac = (float)factor[0];
    // VALIDATED: reciprocal-multiply quantize, f32
    const float rqy = 1.0f / (y_table[lane] * fac);
    const float rqc = 1.0f / (c_table[lane] * fac);

    // ---- phase 2: 6 blocks, explicit ILP-6, frozen k-ascending FMA chains ----
    SETUP(0) SETUP(1) SETUP(2) SETUP(3) SETUP(4) SETUP(5)

    GROUP(0)  GROUP(1)  GROUP(2)  GROUP(3)
    GROUP(4)  GROUP(5)  GROUP(6)  GROUP(7)
    GROUP(8)  GROUP(9)  GROUP(10) GROUP(11)
    GROUP(12) GROUP(13) GROUP(14) GROUP(15)

    FIN(0) FIN(1) FIN(2) FIN(3) FIN(4) FIN(5)
}

extern "C" void kernel_launch(void* const* d_in, const int* in_sizes, int n_in,
                              void* d_out, int out_size, void* d_ws, size_t ws_size,
                              hipStream_t stream)
{
    const float* image   = (const float*)d_in[0];
    const float* matrix  = (const float*)d_in[1];
    const float* shiftv  = (const float*)d_in[2];
    const float* y_table = (const float*)d_in[3];
    const float* c_table = (const float*)d_in[4];
    const float* dct_t   = (const float*)d_in[5];
    const float* dct_s   = (const float*)d_in[6];
    const int*   factor  = (const int*)d_in[7];
    jpeg_compress<<<dim3(16384), dim3(256), 0, stream>>>(
        image, matrix, shiftv, y_table, c_table, dct_t, dct_s, factor,
        (float*)d_out);
}